// Round 1
// baseline (14691.570 us; speedup 1.0000x reference)
//
#include <hip/hip_runtime.h>
#include <hip/hip_bf16.h>

typedef __attribute__((ext_vector_type(8))) short bf16x8;
typedef __attribute__((ext_vector_type(4))) float f32x4;
typedef __hip_bfloat16 bf16;

#define ALPHA_F 0.42728713f
#define LN_EPS 1e-3f

__device__ __forceinline__ float silu_f(float x) { return x / (1.0f + __expf(-x)); }
__device__ __forceinline__ float mish_f(float x) {
  float sp = (x > 20.0f) ? x : log1pf(__expf(x));
  return x * tanhf(sp);
}

__device__ __forceinline__ void mfma16(f32x4& acc, bf16x8 a, bf16x8 b) {
  asm("v_mfma_f32_16x16x32_bf16 %0, %1, %2, %0" : "+v"(acc) : "v"(a), "v"(b));
}

#define GLOAD_LDS16(gp, lp)                                                              \
  __builtin_amdgcn_global_load_lds((__attribute__((address_space(1))) void*)(void*)(gp), \
                                   (__attribute__((address_space(3))) void*)(void*)(lp), \
                                   16, 0, 0)

// ---------------- weight transpose+convert: W[K,N] f32 -> Wt[N,K] bf16 ----------------
__global__ __launch_bounds__(256) void transpose_cvt(const float* __restrict__ W,
                                                     bf16* __restrict__ Wt, int K, int N) {
  __shared__ float tile[32][33];
  int tx = threadIdx.x & 31, ty = threadIdx.x >> 5;
  int nb = blockIdx.x * 32, kb = blockIdx.y * 32;
#pragma unroll
  for (int i = 0; i < 4; ++i) {
    tile[ty + i * 8][tx] = W[(size_t)(kb + ty + i * 8) * N + nb + tx];
  }
  __syncthreads();
#pragma unroll
  for (int i = 0; i < 4; ++i) {
    Wt[(size_t)(nb + ty + i * 8) * K + kb + tx] = __float2bfloat16(tile[tx][ty + i * 8]);
  }
}

__global__ __launch_bounds__(256) void cvt_f32_bf16_k(const float* __restrict__ in,
                                                      bf16* __restrict__ out, long long n) {
  long long i = ((long long)blockIdx.x * 256 + threadIdx.x) * 4;
  if (i + 3 < n) {
    float4 v = *(const float4*)(in + i);
    out[i + 0] = __float2bfloat16(v.x);
    out[i + 1] = __float2bfloat16(v.y);
    out[i + 2] = __float2bfloat16(v.z);
    out[i + 3] = __float2bfloat16(v.w);
  }
}

__global__ __launch_bounds__(256) void pack3_k(const float* __restrict__ a,
                                               const float* __restrict__ b,
                                               const float* __restrict__ c,
                                               float* __restrict__ o) {
  int i = blockIdx.x * 256 + threadIdx.x;
  if (i < 1024) o[i] = a[i];
  else if (i < 2048) o[i] = b[i - 1024];
  else if (i < 3072) o[i] = c[i - 2048];
}

__global__ __launch_bounds__(1) void sentinel_k(float* __restrict__ o) { o[0] = 1.2345e7f; }

// ---------------- main bf16 MFMA GEMM: C[M,N] = A[M,K] @ Bt[N,K]^T (+bias, act) --------
// ACT: 0 none, 1 silu, 2 mish. OUTBF16: write Cb else Cf.
template <int ACT, bool OUTBF16, bool BIAS>
__global__ __launch_bounds__(256) void gemm_tn(const bf16* __restrict__ A,
                                               const bf16* __restrict__ Bt,
                                               const float* __restrict__ bias,
                                               float* __restrict__ Cf, bf16* __restrict__ Cb,
                                               int M, int N, int K) {
  __shared__ __align__(128) short As[128 * 32];
  __shared__ __align__(128) short Bs[128 * 32];
  int t = threadIdx.x;
  int lane = t & 63, wave = t >> 6;
  int m0 = blockIdx.y * 128, n0 = blockIdx.x * 128;
  int wr = wave >> 1, wc = wave & 1;
  int fr = lane & 15;
  int fk = (lane >> 4) << 3;

  f32x4 acc[4][4] = {};

  int c0 = t, row0 = c0 >> 2, ko0 = (c0 & 3) << 3;
  int c1 = 256 + t, row1 = c1 >> 2, ko1 = (c1 & 3) << 3;
  short* lpA0 = As + (size_t)(wave * 64) * 8;
  short* lpA1 = As + (size_t)(256 + wave * 64) * 8;
  short* lpB0 = Bs + (size_t)(wave * 64) * 8;
  short* lpB1 = Bs + (size_t)(256 + wave * 64) * 8;

  const short* ArdBase = As + ((wr * 64 + fr) * 32 + fk);
  const short* BrdBase = Bs + ((wc * 64 + fr) * 32 + fk);

  const bf16* Ag0 = A + (size_t)(m0 + row0) * K + ko0;
  const bf16* Ag1 = A + (size_t)(m0 + row1) * K + ko1;
  const bf16* Bg0 = Bt + (size_t)(n0 + row0) * K + ko0;
  const bf16* Bg1 = Bt + (size_t)(n0 + row1) * K + ko1;

  int nk = K >> 5;
  for (int kt = 0; kt < nk; ++kt) {
    int k0 = kt << 5;
    GLOAD_LDS16(Ag0 + k0, lpA0);
    GLOAD_LDS16(Ag1 + k0, lpA1);
    GLOAD_LDS16(Bg0 + k0, lpB0);
    GLOAD_LDS16(Bg1 + k0, lpB1);
    __syncthreads();
    bf16x8 af[4], bfv[4];
#pragma unroll
    for (int a = 0; a < 4; ++a) af[a] = *(const bf16x8*)(ArdBase + a * 512);
#pragma unroll
    for (int b = 0; b < 4; ++b) bfv[b] = *(const bf16x8*)(BrdBase + b * 512);
#pragma unroll
    for (int a = 0; a < 4; ++a)
#pragma unroll
      for (int b = 0; b < 4; ++b) mfma16(acc[a][b], af[a], bfv[b]);
    __syncthreads();
  }
  asm volatile("s_nop 7\n\ts_nop 7");
  int lr = (lane >> 4) << 2;
  int lc = lane & 15;
#pragma unroll
  for (int a = 0; a < 4; ++a) {
#pragma unroll
    for (int b = 0; b < 4; ++b) {
      int col = n0 + wc * 64 + b * 16 + lc;
      float bv = 0.0f;
      if constexpr (BIAS) bv = bias[col];
#pragma unroll
      for (int j = 0; j < 4; ++j) {
        int rowi = m0 + wr * 64 + a * 16 + lr + j;
        float v = acc[a][b][j] + bv;
        if constexpr (ACT == 1) v = silu_f(v);
        if constexpr (ACT == 2) v = mish_f(v);
        if constexpr (OUTBF16) Cb[(size_t)rowi * N + col] = __float2bfloat16(v);
        else Cf[(size_t)rowi * N + col] = v;
      }
    }
  }
}

// ---------------- c = x @ sc_w : [8192,1024]f32 @ [1024,32]f32 -> [8192,32]f32 ---------
__global__ __launch_bounds__(256) void c_kernel(const float* __restrict__ x,
                                                const float* __restrict__ scw,
                                                float* __restrict__ cout) {
  __shared__ float Xs[8][1024];
  int t = threadIdx.x;
  int row0 = blockIdx.x * 8;
#pragma unroll
  for (int i = 0; i < 32; ++i) {
    int idx = t + i * 256;
    Xs[idx >> 10][idx & 1023] = x[(size_t)row0 * 1024 + idx];
  }
  __syncthreads();
  int r = t >> 5, n = t & 31;
  float acc = 0.0f;
#pragma unroll 4
  for (int k = 0; k < 1024; ++k) acc += Xs[r][k] * scw[k * 32 + n];
  cout[(size_t)(row0 + r) * 32 + n] = acc;
}

// ---------------- h = LN(silu(c @ sh1_w + b)) : [128,2048]@[2048,256] -> bf16[128,256] -
__global__ __launch_bounds__(256) void h_kernel(const float* __restrict__ c,
                                                const float* __restrict__ w,
                                                const float* __restrict__ bias,
                                                const float* __restrict__ gam,
                                                const float* __restrict__ bet,
                                                bf16* __restrict__ hb) {
  __shared__ float Cs[2048];
  __shared__ float rsm[4], rs2[4], st2[2];
  int t = threadIdx.x, row = blockIdx.x;
#pragma unroll
  for (int i = 0; i < 8; ++i) Cs[t + i * 256] = c[(size_t)row * 2048 + t + i * 256];
  __syncthreads();
  float acc = bias[t];
#pragma unroll 4
  for (int k = 0; k < 2048; ++k) acc += Cs[k] * w[(size_t)k * 256 + t];
  float sv = silu_f(acc);
  float s = sv, s2 = sv * sv;
#pragma unroll
  for (int o = 32; o > 0; o >>= 1) { s += __shfl_down(s, o); s2 += __shfl_down(s2, o); }
  if ((t & 63) == 0) { rsm[t >> 6] = s; rs2[t >> 6] = s2; }
  __syncthreads();
  if (t == 0) {
    float a = rsm[0] + rsm[1] + rsm[2] + rsm[3];
    float b2 = rs2[0] + rs2[1] + rs2[2] + rs2[3];
    float m = a * (1.0f / 256.0f);
    st2[0] = m;
    st2[1] = rsqrtf(b2 * (1.0f / 256.0f) - m * m + LN_EPS);
  }
  __syncthreads();
  float y = (sv - st2[0]) * st2[1] * gam[t] + bet[t];
  hb[(size_t)row * 256 + t] = __float2bfloat16(y);
}

// ---------------- LN over 8192 cols (smolgen g) -> bf16 --------------------------------
__global__ __launch_bounds__(1024) void ln8192_kernel(const float* __restrict__ gpre,
                                                      const float* __restrict__ gam,
                                                      const float* __restrict__ bet,
                                                      bf16* __restrict__ gb) {
  __shared__ float rsm[16], rs2[16], st2[2];
  int t = threadIdx.x, row = blockIdx.x;
  const float* p = gpre + (size_t)row * 8192;
  float v[8];
  float s = 0.0f, s2 = 0.0f;
#pragma unroll
  for (int i = 0; i < 8; ++i) {
    v[i] = p[t + i * 1024];
    s += v[i];
    s2 += v[i] * v[i];
  }
#pragma unroll
  for (int o = 32; o > 0; o >>= 1) { s += __shfl_down(s, o); s2 += __shfl_down(s2, o); }
  int lane = t & 63, w = t >> 6;
  if (lane == 0) { rsm[w] = s; rs2[w] = s2; }
  __syncthreads();
  if (t == 0) {
    float a = 0.0f, b2 = 0.0f;
#pragma unroll
    for (int i = 0; i < 16; ++i) { a += rsm[i]; b2 += rs2[i]; }
    float m = a * (1.0f / 8192.0f);
    st2[0] = m;
    st2[1] = rsqrtf(b2 * (1.0f / 8192.0f) - m * m + LN_EPS);
  }
  __syncthreads();
  float m = st2[0], r = st2[1];
#pragma unroll
  for (int i = 0; i < 8; ++i) {
    int n = t + i * 1024;
    gb[(size_t)row * 8192 + n] = __float2bfloat16((v[i] - m) * r * gam[n] + bet[n]);
  }
}

// ---------------- residual + LN over 1024 cols: out = LN(base + delta*ALPHA) -----------
__global__ __launch_bounds__(256) void ln_residual_kernel(const float* __restrict__ base,
                                                          const float* __restrict__ delta,
                                                          const float* __restrict__ gam,
                                                          const float* __restrict__ bet,
                                                          float* __restrict__ outf,
                                                          bf16* __restrict__ outb) {
  __shared__ float rsm[4], rs2[4], st2[2];
  int t = threadIdx.x, row = blockIdx.x;
  const float* bp = base + (size_t)row * 1024;
  const float* dp = delta + (size_t)row * 1024;
  float v[4];
  float s = 0.0f, s2 = 0.0f;
#pragma unroll
  for (int i = 0; i < 4; ++i) {
    int cc = t + i * 256;
    v[i] = bp[cc] + dp[cc] * ALPHA_F;
    s += v[i];
    s2 += v[i] * v[i];
  }
#pragma unroll
  for (int o = 32; o > 0; o >>= 1) { s += __shfl_down(s, o); s2 += __shfl_down(s2, o); }
  if ((t & 63) == 0) { rsm[t >> 6] = s; rs2[t >> 6] = s2; }
  __syncthreads();
  if (t == 0) {
    float a = rsm[0] + rsm[1] + rsm[2] + rsm[3];
    float b2 = rs2[0] + rs2[1] + rs2[2] + rs2[3];
    float m = a * (1.0f / 1024.0f);
    st2[0] = m;
    st2[1] = rsqrtf(b2 * (1.0f / 1024.0f) - m * m + LN_EPS);
  }
  __syncthreads();
  float m = st2[0], r = st2[1];
  float* of = outf + (size_t)row * 1024;
  bf16* ob = outb + (size_t)row * 1024;
#pragma unroll
  for (int i = 0; i < 4; ++i) {
    int cc = t + i * 256;
    float y = (v[i] - m) * r * gam[cc] + bet[cc];
    of[cc] = y;
    ob[cc] = __float2bfloat16(y);
  }
}

// ---------------- fused attention per (b,h): S=QK^T/sqrt(32)+sw, softmax, AV -----------
__global__ __launch_bounds__(256) void attn_kernel(const bf16* __restrict__ qkv,
                                                   const float* __restrict__ sw,
                                                   bf16* __restrict__ avb) {
  __shared__ float Qs[64][33], Ks[64][33], Vs[64][33];
  __shared__ float S[64][65];
  __shared__ float rowm[64], rowr[64];
  int t = threadIdx.x;
  int bh = blockIdx.x;
  int b = bh >> 5, h = bh & 31;
  size_t qbase = (size_t)b * 64 * 3072 + h * 32;
#pragma unroll
  for (int i = 0; i < 8; ++i) {
    int idx = t + i * 256;  // 0..2047
    int q = idx >> 5, d = idx & 31;
    size_t g = qbase + (size_t)q * 3072 + d;
    Qs[q][d] = __bfloat162float(qkv[g]);
    Ks[q][d] = __bfloat162float(qkv[g + 1024]);
    Vs[q][d] = __bfloat162float(qkv[g + 2048]);
  }
  __syncthreads();
  const float* swrow = sw + (size_t)bh * 4096;
#pragma unroll
  for (int i = 0; i < 16; ++i) {
    int idx = t + i * 256;
    int q = idx >> 6, k = idx & 63;
    float s = 0.0f;
#pragma unroll
    for (int d = 0; d < 32; ++d) s += Qs[q][d] * Ks[k][d];
    S[q][k] = s * 0.17677669529663687f + swrow[idx];
  }
  __syncthreads();
  if (t < 64) {
    float m = -1e30f;
    for (int k = 0; k < 64; ++k) m = fmaxf(m, S[t][k]);
    float sum = 0.0f;
    for (int k = 0; k < 64; ++k) sum += __expf(S[t][k] - m);
    rowm[t] = m;
    rowr[t] = 1.0f / sum;
  }
  __syncthreads();
#pragma unroll
  for (int i = 0; i < 16; ++i) {
    int idx = t + i * 256;
    int q = idx >> 6, k = idx & 63;
    S[q][k] = __expf(S[q][k] - rowm[q]) * rowr[q];
  }
  __syncthreads();
#pragma unroll
  for (int i = 0; i < 8; ++i) {
    int idx = t + i * 256;
    int q = idx >> 5, d = idx & 31;
    float s = 0.0f;
#pragma unroll
    for (int k = 0; k < 64; ++k) s += S[q][k] * Vs[k][d];
    avb[(size_t)(b * 64 + q) * 1024 + h * 32 + d] = __float2bfloat16(s);
  }
}

extern "C" void kernel_launch(void* const* d_in, const int* in_sizes, int n_in,
                              void* d_out, int out_size, void* d_ws, size_t ws_size,
                              hipStream_t stream) {
  const float* x_in   = (const float*)d_in[0];
  const float* wq_w   = (const float*)d_in[1];
  const float* wq_b   = (const float*)d_in[2];
  const float* wk_w   = (const float*)d_in[3];
  const float* wk_b   = (const float*)d_in[4];
  const float* wv_w   = (const float*)d_in[5];
  const float* wv_b   = (const float*)d_in[6];
  const float* wo_w   = (const float*)d_in[7];
  const float* wo_b   = (const float*)d_in[8];
  const float* sc_w   = (const float*)d_in[9];
  const float* sh1_w  = (const float*)d_in[10];
  const float* sh1_b  = (const float*)d_in[11];
  const float* sln1_g = (const float*)d_in[12];
  const float* sln1_b = (const float*)d_in[13];
  const float* sgf_w  = (const float*)d_in[14];
  const float* sgf_b  = (const float*)d_in[15];
  const float* sln2_g = (const float*)d_in[16];
  const float* sln2_b = (const float*)d_in[17];
  const float* swg_w  = (const float*)d_in[18];
  const float* ffn1_w = (const float*)d_in[19];
  const float* ffn1_b = (const float*)d_in[20];
  const float* ffn2_w = (const float*)d_in[21];
  const float* ffn2_b = (const float*)d_in[22];
  const float* n1_g   = (const float*)d_in[23];
  const float* n1_b   = (const float*)d_in[24];
  const float* n2_g   = (const float*)d_in[25];
  const float* n2_b   = (const float*)d_in[26];

  char* ws = (char*)d_ws;
  size_t off = 0;
  auto alloc = [&](size_t bytes) -> void* {
    void* p = ws + off;
    off += (bytes + 255) & ~(size_t)255;
    return p;
  };
  bf16*  xb    = (bf16*)alloc(8192ULL * 1024 * 2);
  float* P0    = (float*)alloc(8192ULL * 1024 * 4);
  float* P1    = (float*)alloc(8192ULL * 1024 * 4);
  float* Tbuf  = (float*)alloc(8192ULL * 1024 * 4);
  bf16*  Wqkv  = (bf16*)alloc(3072ULL * 1024 * 2);
  float* bqkv  = (float*)alloc(3072ULL * 4);
  bf16*  Wo    = (bf16*)alloc(1024ULL * 1024 * 2);
  bf16*  Wf1   = (bf16*)alloc(1536ULL * 1024 * 2);
  bf16*  Wf2   = (bf16*)alloc(1024ULL * 1536 * 2);
  bf16*  Wsgf  = (bf16*)alloc(8192ULL * 256 * 2);
  bf16*  Wswg  = (bf16*)alloc(4096ULL * 256 * 2);
  bf16*  qkvb  = (bf16*)alloc(8192ULL * 3072 * 2);
  float* cbuf  = (float*)alloc(8192ULL * 32 * 4);
  bf16*  hbb   = (bf16*)alloc(128ULL * 256 * 2);
  float* gpre  = (float*)alloc(128ULL * 8192 * 4);
  bf16*  gbb   = (bf16*)alloc(128ULL * 8192 * 2);
  float* swb   = (float*)alloc(4096ULL * 4096 * 4);
  bf16*  avb   = (bf16*)alloc(8192ULL * 1024 * 2);
  bf16*  out1b = (bf16*)alloc(8192ULL * 1024 * 2);
  bf16*  f1b   = (bf16*)alloc(8192ULL * 1536 * 2);
  if (off > ws_size) {
    sentinel_k<<<1, 1, 0, stream>>>((float*)d_out);
    return;
  }

  cvt_f32_bf16_k<<<8192, 256, 0, stream>>>(x_in, xb, 8192LL * 1024);

  for (int l = 0; l < 15; ++l) {
    const float* wq   = wq_w + (size_t)l * 1024 * 1024;
    const float* wk   = wk_w + (size_t)l * 1024 * 1024;
    const float* wv   = wv_w + (size_t)l * 1024 * 1024;
    const float* wo   = wo_w + (size_t)l * 1024 * 1024;
    const float* f1w  = ffn1_w + (size_t)l * 1024 * 1536;
    const float* f2w  = ffn2_w + (size_t)l * 1536 * 1024;
    const float* sgf  = sgf_w + (size_t)l * 256 * 8192;
    const float* swg  = swg_w + (size_t)l * 256 * 4096;
    const float* scw  = sc_w + (size_t)l * 1024 * 32;
    const float* sh1w = sh1_w + (size_t)l * 2048 * 256;

    transpose_cvt<<<dim3(32, 32), 256, 0, stream>>>(wq, Wqkv, 1024, 1024);
    transpose_cvt<<<dim3(32, 32), 256, 0, stream>>>(wk, Wqkv + 1024 * 1024, 1024, 1024);
    transpose_cvt<<<dim3(32, 32), 256, 0, stream>>>(wv, Wqkv + 2048 * 1024, 1024, 1024);
    transpose_cvt<<<dim3(32, 32), 256, 0, stream>>>(wo, Wo, 1024, 1024);
    transpose_cvt<<<dim3(48, 32), 256, 0, stream>>>(f1w, Wf1, 1024, 1536);
    transpose_cvt<<<dim3(32, 48), 256, 0, stream>>>(f2w, Wf2, 1536, 1024);
    transpose_cvt<<<dim3(256, 8), 256, 0, stream>>>(sgf, Wsgf, 256, 8192);
    transpose_cvt<<<dim3(128, 8), 256, 0, stream>>>(swg, Wswg, 256, 4096);
    pack3_k<<<12, 256, 0, stream>>>(wq_b + l * 1024, wk_b + l * 1024, wv_b + l * 1024, bqkv);

    const float* xc = (l == 0) ? x_in : ((l & 1) ? P0 : P1);
    float* Pout = (l & 1) ? P1 : P0;

    // QKV projection
    gemm_tn<0, true, true><<<dim3(24, 64), 256, 0, stream>>>(xb, Wqkv, bqkv, nullptr, qkvb,
                                                             8192, 3072, 1024);
    // smolgen chain
    c_kernel<<<1024, 256, 0, stream>>>(xc, scw, cbuf);
    h_kernel<<<128, 256, 0, stream>>>(cbuf, sh1w, sh1_b + l * 256, sln1_g + l * 256,
                                      sln1_b + l * 256, hbb);
    gemm_tn<1, false, true><<<dim3(64, 1), 256, 0, stream>>>(hbb, Wsgf, sgf_b + (size_t)l * 8192,
                                                             gpre, nullptr, 128, 8192, 256);
    ln8192_kernel<<<128, 1024, 0, stream>>>(gpre, sln2_g + (size_t)l * 8192,
                                            sln2_b + (size_t)l * 8192, gbb);
    gemm_tn<0, false, false><<<dim3(32, 32), 256, 0, stream>>>(gbb, Wswg, nullptr, swb, nullptr,
                                                               4096, 4096, 256);
    // attention
    attn_kernel<<<4096, 256, 0, stream>>>(qkvb, swb, avb);
    // output projection + LN1
    gemm_tn<0, false, true><<<dim3(8, 64), 256, 0, stream>>>(avb, Wo, wo_b + l * 1024, Tbuf,
                                                             nullptr, 8192, 1024, 1024);
    ln_residual_kernel<<<8192, 256, 0, stream>>>(xc, Tbuf, n1_g + l * 1024, n1_b + l * 1024,
                                                 Pout, out1b);
    // FFN + LN2
    gemm_tn<2, true, true><<<dim3(12, 64), 256, 0, stream>>>(out1b, Wf1, ffn1_b + l * 1536,
                                                             nullptr, f1b, 8192, 1536, 1024);
    gemm_tn<0, false, true><<<dim3(8, 64), 256, 0, stream>>>(f1b, Wf2, ffn2_b + l * 1024, Tbuf,
                                                             nullptr, 8192, 1024, 1536);
    float* xnext = (l == 14) ? (float*)d_out : Pout;
    ln_residual_kernel<<<8192, 256, 0, stream>>>(Pout, Tbuf, n2_g + l * 1024, n2_b + l * 1024,
                                                 xnext, xb);
  }
}